// Round 3
// baseline (523.963 us; speedup 1.0000x reference)
//
#include <hip/hip_runtime.h>
#include <hip/hip_bf16.h>

// Problem constants: B=64, T=2048, D=256, U=256 (fp32 in/out)
#define BB 64
#define TT 2048
#define DD 256
#define UU 256
#define MM (BB*TT)          // 131072 GEMM rows
#define NN (3*UU)           // 768 fused output cols (z,r,h)
#define PLANE ((size_t)BB*TT*UU)   // 33554432 elements per projection plane

typedef _Float16 half8 __attribute__((ext_vector_type(8)));
typedef _Float16 half4 __attribute__((ext_vector_type(4)));
typedef float floatx4 __attribute__((ext_vector_type(4)));

// ---------------- fast math helpers ----------------
__device__ inline float fexp2(float x){
#if __has_builtin(__builtin_amdgcn_exp2f)
  return __builtin_amdgcn_exp2f(x);
#else
  return exp2f(x);
#endif
}
__device__ inline float frcp(float x){
#if __has_builtin(__builtin_amdgcn_rcpf)
  return __builtin_amdgcn_rcpf(x);
#else
  return 1.0f/x;
#endif
}
// tanh(a) = 1 - 2/(exp2(2*log2e*a)+1)  (saturates correctly at +-inf)
__device__ inline float ftanh(float a){
  const float TWO_L2E = 2.8853900817779268f;
  return 1.0f - 2.0f*frcp(fexp2(TWO_L2E*a) + 1.0f);
}
__device__ inline float fsigmoid(float a){
  const float L2E = 1.4426950408889634f;
  return frcp(1.0f + fexp2(-L2E*a));
}

// ---------------- kernel 0: weights -> fused transposed f16 [N=768][K=256] ----------------
__global__ __launch_bounds__(256) void prep_kernel(const float* __restrict__ kz,
                                                   const float* __restrict__ kr,
                                                   const float* __restrict__ kh,
                                                   _Float16* __restrict__ K16T){
  int o = blockIdx.x*256 + threadIdx.x;     // 0..196607
  int n = o >> 8;                            // fused col: p*256+u
  int k = o & 255;                           // d
  int p = n >> 8;
  int u = n & 255;
  const float* w = (p==0) ? kz : ((p==1) ? kr : kh);
  K16T[o] = (_Float16)w[k*UU + u];
}

// ---------------- kernel 1: GEMM  -> P[p][b*U+u][t] (t-major, f16) ----------------
#define BM 128
#define BN 128
#define BK 32
// LDS layout (conflict-free, global_load_lds-compatible):
//   As16 = smem[0..4095]      : [kq][m][8]  (kq = k-octet 0..3, m = 0..127)
//   Bs16 = smem[4096..8191]   : [kq][n][8]
//   Ct   = smem[0..8703]      : epilogue reuse, [64][136] f16 (136 = 128 + 8 pad)
// Frag reads hit 256B-contiguous runs per 16-lane group -> 0 bank conflicts
// (old Bs [n][k] row stride 64B was an 8-way conflict: 9.4M cyc/dispatch).
#define AS_OFF 0
#define BS_OFF 4096
#define CT_LDT 136

__global__ __launch_bounds__(256) void gemm_kernel(const float* __restrict__ X,
                                                   const _Float16* __restrict__ K16T,
                                                   const float* __restrict__ bz,
                                                   const float* __restrict__ br,
                                                   const float* __restrict__ bh,
                                                   _Float16* __restrict__ P){
  __shared__ __align__(16) _Float16 smem[8704];   // 17408 B
  const int tid = threadIdx.x;

  // ---- bijective XCD-aware remap (6144 blocks = 8 XCDs x 768) ----
  // XCD k owns M-panels [k*128, k*128+128); the 6 N-tiles of a panel are
  // temporally adjacent so the 128KB A-panel is fetched once per L2, and
  // the whole 384KB K16T stays L2-resident. (round 1: FETCH 397MB -> 68MB)
  const int l   = blockIdx.y*6 + blockIdx.x;   // hw linear id (x fastest)
  const int xcd = l & 7;
  const int idx = l >> 3;                      // 0..767 within xcd
  const int pnl = idx / 6;                     // 0..127: M panel within chunk
  const int by  = xcd*128 + pnl;               // logical M tile
  const int bx  = idx - pnl*6;                 // logical N tile 0..5
  const int rowBase = by*BM;
  const int nBase   = bx*BN;

  const int wave = tid >> 6, lane = tid & 63;
  const int wm = wave & 1, wn = wave >> 1;     // 2x2 wave grid, each 64x64
  const int lrow = lane & 15, lkq = lane >> 4; // frag row / k-octet

  floatx4 acc[4][4] = {};

  // A staging: thread = (row, k-half). Loads one full 64B line of X per iter,
  // writes two [kq][m] cells -> ds_write lanes are 16B-consecutive (0-conflict).
  const int arow = tid & 127;
  const int asel = tid >> 7;                   // 0/1: k-cols asel*16..+15
  const float* aptr = X + (size_t)(rowBase + arow)*DD + asel*16;
  _Float16* aw0 = smem + AS_OFF + ((asel*2 + 0)*128 + arow)*8;
  _Float16* aw1 = smem + AS_OFF + ((asel*2 + 1)*128 + arow)*8;

  // B staging: chunk c=tid -> (kq=tid>>7, n=tid&127); c=tid+256 -> kq+2 (=+16 halves)
  const _Float16* bsrc = K16T + (size_t)(nBase + (tid & 127))*DD + (tid >> 7)*8;

  for (int k0 = 0; k0 < DD; k0 += BK) {
    __syncthreads();   // protect LDS from previous iteration's readers
    // --- A tile: fp32 loads first; the cvt's vmcnt wait leaves the two B
    //     global_load_lds (issued after) in flight until the barrier ---
    floatx4 a0 = *(const floatx4*)(aptr + k0);
    floatx4 a1 = *(const floatx4*)(aptr + k0 + 4);
    floatx4 a2 = *(const floatx4*)(aptr + k0 + 8);
    floatx4 a3 = *(const floatx4*)(aptr + k0 + 12);
    // --- B tile: async global->LDS (f16, 2 x 16B per thread, lane-linear dst) ---
    __builtin_amdgcn_global_load_lds(
        (const __attribute__((address_space(1))) void*)(bsrc + k0),
        (__attribute__((address_space(3))) void*)(smem + BS_OFF + tid*8),
        16, 0, 0);
    __builtin_amdgcn_global_load_lds(
        (const __attribute__((address_space(1))) void*)(bsrc + k0 + 16),
        (__attribute__((address_space(3))) void*)(smem + BS_OFF + (tid + 256)*8),
        16, 0, 0);
    // --- cvt + LDS write for A ---
    half8 pk0, pk1;
    #pragma unroll
    for (int q = 0; q < 4; q++){
      pk0[q]   = (_Float16)a0[q];
      pk0[4+q] = (_Float16)a1[q];
      pk1[q]   = (_Float16)a2[q];
      pk1[4+q] = (_Float16)a3[q];
    }
    *(half8*)aw0 = pk0;
    *(half8*)aw1 = pk1;
    __syncthreads();
    // --- fragments + MFMA (BK=32 == one K step) ---
    half8 af[4], bf[4];
    #pragma unroll
    for (int i = 0; i < 4; i++)
      af[i] = *(const half8*)&smem[AS_OFF + (lkq*128 + wm*64 + i*16 + lrow)*8];
    #pragma unroll
    for (int j = 0; j < 4; j++)
      bf[j] = *(const half8*)&smem[BS_OFF + (lkq*128 + wn*64 + j*16 + lrow)*8];
    #pragma unroll
    for (int i = 0; i < 4; i++)
      #pragma unroll
      for (int j = 0; j < 4; j++)
        acc[i][j] = __builtin_amdgcn_mfma_f32_16x16x32_f16(af[i], bf[j], acc[i][j], 0, 0, 0);
  }

  // --- epilogue: LDS-staged transpose -> full-line coalesced stores ---
  // Old path stored half4 (8B) at 4KB stride: 64 distinct lines per wave-store,
  // 25M 8B L2 write transactions/dispatch. Now: stage [u][t] tile in LDS,
  // stream out 64B contiguous per thread (line-granular writes, 8x fewer ops).
  const int p = bx >> 1;                // plane (z/r/h); BN=128 never crosses planes
  const int ub = (bx & 1) * 128;        // u base within plane
  const float* bias = (p==0) ? bz : ((p==1) ? br : bh);
  _Float16* Pp = P + (size_t)p * PLANE;
  const int bidx  = rowBase >> 11;      // batch index (uniform per block)
  const int trow0 = rowBase & 2047;     // t base of this block
  const int u_r = tid >> 2, tc = tid & 3;

  #pragma unroll
  for (int h = 0; h < 2; h++){
    __syncthreads();                    // Ct region free (K-loop / prev half done)
    if (wn == h){                       // 2 waves own this u-half
      #pragma unroll
      for (int j = 0; j < 4; j++){
        const int u_l = j*16 + lrow;
        const float bv = bias[ub + h*64 + u_l];
        #pragma unroll
        for (int i = 0; i < 4; i++){
          half4 v;
          #pragma unroll
          for (int r = 0; r < 4; r++)
            v[r] = (_Float16)(acc[i][j][r] + bv);   // t_l = wm*64 + i*16 + lkq*4 + r
          *(half4*)&smem[u_l*CT_LDT + wm*64 + i*16 + lkq*4] = v;
        }
      }
    }
    __syncthreads();
    // all 256 threads: thread covers (u_r, 32 t's) = 64B contiguous
    _Float16* dst = Pp + (size_t)(bidx*UU + ub + h*64 + u_r)*TT + trow0 + tc*32;
    const _Float16* srcp = smem + u_r*CT_LDT + tc*32;
    #pragma unroll
    for (int q = 0; q < 4; q++)
      *(half8*)(dst + q*8) = *(const half8*)(srcp + q*8);
  }
}

// ---------------- kernel 2: time scan, one lane per (b,u), t-major P ----------------
#define PF 16          // timesteps per chunk
#define NBUF 4         // register ring depth (prefetch distance 3 chunks)
__global__ __launch_bounds__(64) void scan_kernel(const _Float16* __restrict__ P,
                                                  const float* __restrict__ mz,
                                                  const float* __restrict__ mr,
                                                  float* __restrict__ out){
  const int ci = blockIdx.x*64 + threadIdx.x;   // chain id: b*256+u
  const int b = ci >> 8;
  const int u = ci & 255;
  const half8* pz = (const half8*)(P + (size_t)ci*TT);
  const half8* pr = (const half8*)(P + PLANE + (size_t)ci*TT);
  const half8* ph = (const half8*)(P + 2*PLANE + (size_t)ci*TT);
  float* po = out + (size_t)b*(TT*UU) + u;
  const float vmz = mz[u], vmr = mr[u];
  float h = 0.0f;

  half8 qz[NBUF][2], qr[NBUF][2], qh[NBUF][2];

#define LOADC(buf, c) do { \
    qz[buf][0] = pz[(c)*2];   qz[buf][1] = pz[(c)*2+1]; \
    qr[buf][0] = pr[(c)*2];   qr[buf][1] = pr[(c)*2+1]; \
    qh[buf][0] = ph[(c)*2];   qh[buf][1] = ph[(c)*2+1]; \
  } while(0)

#define PROC(buf, c) do { \
    _Pragma("unroll") \
    for (int i = 0; i < PF; i++){ \
      float xz = (float)qz[buf][i>>3][i&7]; \
      float xr = (float)qr[buf][i>>3][i&7]; \
      float xh = (float)qh[buf][i>>3][i&7]; \
      float r  = ftanh(xr + h*vmr) + 1.0f; \
      float z  = fsigmoid(xz + h*vmz); \
      float hh = ftanh(xh + r*h); \
      h = (1.0f - z)*hh + z*h; \
      po[(size_t)((c)*PF + i)*UU] = h; \
    } \
    if ((c) + NBUF < NC) LOADC(buf, (c) + NBUF); \
  } while(0)

  const int NC = TT/PF;   // 128 chunks
  LOADC(0, 0); LOADC(1, 1); LOADC(2, 2); LOADC(3, 3);
  for (int c = 0; c < NC; c += NBUF){
    PROC(0, c);
    PROC(1, c+1);
    PROC(2, c+2);
    PROC(3, c+3);
  }
#undef LOADC
#undef PROC
}

extern "C" void kernel_launch(void* const* d_in, const int* in_sizes, int n_in,
                              void* d_out, int out_size, void* d_ws, size_t ws_size,
                              hipStream_t stream) {
  (void)in_sizes; (void)n_in; (void)out_size; (void)ws_size;
  const float* x  = (const float*)d_in[0];
  const float* kz = (const float*)d_in[1];
  const float* kr = (const float*)d_in[2];
  const float* kh = (const float*)d_in[3];
  const float* mz = (const float*)d_in[4];
  const float* mr = (const float*)d_in[5];
  const float* bz = (const float*)d_in[6];
  const float* br = (const float*)d_in[7];
  const float* bh = (const float*)d_in[8];
  float* out = (float*)d_out;

  // ws layout: [K16T: 768*256 f16 = 393216 B][P: 3 planes * 33554432 f16 = 201326592 B]
  _Float16* K16T = (_Float16*)d_ws;
  _Float16* P    = (_Float16*)((char*)d_ws + 393216);

  hipLaunchKernelGGL(prep_kernel, dim3(NN*DD/256), dim3(256), 0, stream, kz, kr, kh, K16T);
  hipLaunchKernelGGL(gemm_kernel, dim3(NN/BN, MM/BM), dim3(256), 0, stream,
                     x, K16T, bz, br, bh, P);
  hipLaunchKernelGGL(scan_kernel, dim3(256), dim3(64), 0, stream, P, mz, mr, out);
}